// Round 2
// baseline (189.553 us; speedup 1.0000x reference)
//
#include <hip/hip_runtime.h>

// Problem constants (from reference setup_inputs)
#define B_   32
#define T_   4096
#define D_   128
#define TU   512
#define M_   8
#define O_   64      // Dout
#define DCH  16      // D-chunk per block
#define NCH  8       // number of D-chunks (D_/DCH)
#define PAD  17      // LDS leading-dim pad: (17u+d)%32 conflict-free both phases
#define BN_EPS 1e-5f

// ---------------------------------------------------------------------------
// K1: fold BN + conv + fc into Weff[8][128] and beff[8], stored in ws.
// ws layout (floats): [0,1024) Weff, [1024,1032) beff
// ---------------------------------------------------------------------------
__global__ void prep_kernel(const float* __restrict__ bn_gamma,
                            const float* __restrict__ bn_beta,
                            const float* __restrict__ bn_mean,
                            const float* __restrict__ bn_var,
                            const float* __restrict__ conv_w,
                            const float* __restrict__ conv_b,
                            const float* __restrict__ fc_w,
                            const float* __restrict__ fc_b,
                            float* __restrict__ ws) {
    __shared__ float wraw[M_ * D_];
    __shared__ float shift_s[D_];
    int tid = threadIdx.x;  // 256 threads
    for (int p = tid; p < M_ * D_; p += 256) {
        int m = p >> 7, d = p & (D_ - 1);
        float s = 0.f;
        for (int o = 0; o < O_; ++o) s += fc_w[m * O_ + o] * conv_w[o * D_ + d];
        wraw[p] = s;
        float sc = bn_gamma[d] * rsqrtf(bn_var[d] + BN_EPS);
        ws[p] = s * sc;
    }
    if (tid < D_) {
        float sc = bn_gamma[tid] * rsqrtf(bn_var[tid] + BN_EPS);
        shift_s[tid] = bn_beta[tid] - bn_mean[tid] * sc;
    }
    __syncthreads();
    if (tid < M_) {
        float s = fc_b[tid];
        for (int o = 0; o < O_; ++o) s += fc_w[tid * O_ + o] * conv_b[o];
        for (int d = 0; d < D_; ++d) s += shift_s[d] * wraw[tid * D_ + d];
        ws[M_ * D_ + tid] = s;
    }
}

// ---------------------------------------------------------------------------
// K2: out[b,u,m] = beff[m]  (full overwrite; scatter kernel atomicAdds on top)
// ---------------------------------------------------------------------------
__global__ void init_out_kernel(const float* __restrict__ ws,
                                float* __restrict__ out) {
    int i = blockIdx.x * 256 + threadIdx.x;  // grid covers B_*TU*M_ exactly
    out[i] = ws[M_ * D_ + (i & (M_ - 1))];
}

// ---------------------------------------------------------------------------
// K3: per-(batch b, d-chunk c) block:
//   phase 1: scatter-max masked positive feats into LDS hidden[512][16] (uint bits)
//   phase 2: partial[u][m] = sum_{d in chunk} hidden[u][d]*Weff[m][d], atomicAdd out
//
// XCD swizzle: block i -> xcd = i&7 (HW maps consecutive ids round-robin over
// 8 XCDs). We place ALL 8 chunk-blocks of a batch on ONE XCD so each 516 B
// row is fetched from HBM once and the other 7 chunks hit that XCD's L2:
//   b = (i&7) + 8*((i>>3)&3)   (batch b runs on XCD b%8; 4 batches per XCD)
//   c = i>>5
// ---------------------------------------------------------------------------
__global__ __launch_bounds__(1024) void scatter_mm_kernel(
    const float* __restrict__ x,        // (B,T,129): [...,0]=tw, [...,1:]=feats
    const int*   __restrict__ mask,     // (B,T) as int32
    const float* __restrict__ tw_uniq,  // (B,Tu)
    const float* __restrict__ ws,       // Weff + beff
    float*       __restrict__ out) {    // (B,Tu,M)
    __shared__ unsigned hid[TU * PAD];  // 34,816 B
    __shared__ float wsm[M_ * DCH];
    const int i = blockIdx.x;           // 0..255
    const int b = (i & 7) + 8 * ((i >> 3) & 3);
    const int c = i >> 5;               // 0..7
    const int tid = threadIdx.x;

    for (int p = tid; p < TU * PAD; p += 1024) hid[p] = 0u;
    if (tid < M_ * DCH) {
        int m = tid / DCH, d = tid % DCH;
        wsm[tid] = ws[m * D_ + c * DCH + d];
    }
    __syncthreads();

    const float* xb = x + (size_t)b * T_ * (D_ + 1);
    const int*   mb = mask + b * T_;
    const float  u0 = tw_uniq[b * TU];

    const int dl = tid & (DCH - 1);   // 0..15: d within chunk
    const int g  = tid >> 4;          // 0..63: row group
#pragma unroll 4
    for (int t = g; t < T_; t += 64) {
        const float* row = xb + (size_t)t * (D_ + 1);
        float fv  = row[1 + c * DCH + dl];
        float twf = row[0];           // broadcast within the 16-lane group
        int   mk  = mb[t];
        if (mk != 0 && fv > 0.0f) {
            int u = (int)(twf - u0);
            u = min(max(u, 0), TU - 1);
            atomicMax(&hid[u * PAD + dl], __float_as_uint(fv));
        }
    }
    __syncthreads();

    // epilogue: thread -> (u = tid&511, mh = tid>>9 selects m in [4*mh, 4*mh+4))
    const int u  = tid & (TU - 1);
    const int mh = tid >> 9;
    float a0 = 0.f, a1 = 0.f, a2 = 0.f, a3 = 0.f;
#pragma unroll
    for (int d = 0; d < DCH; ++d) {
        float h = __uint_as_float(hid[u * PAD + d]);  // (17u+d)%32: conflict-free
        a0 += h * wsm[(mh * 4 + 0) * DCH + d];
        a1 += h * wsm[(mh * 4 + 1) * DCH + d];
        a2 += h * wsm[(mh * 4 + 2) * DCH + d];
        a3 += h * wsm[(mh * 4 + 3) * DCH + d];
    }
    float* op = out + ((size_t)(b * TU + u)) * M_ + mh * 4;
    atomicAdd(op + 0, a0);
    atomicAdd(op + 1, a1);
    atomicAdd(op + 2, a2);
    atomicAdd(op + 3, a3);
}

extern "C" void kernel_launch(void* const* d_in, const int* in_sizes, int n_in,
                              void* d_out, int out_size, void* d_ws, size_t ws_size,
                              hipStream_t stream) {
    const float* x        = (const float*)d_in[0];   // (32,4096,129) f32
    const int*   mask     = (const int*)  d_in[1];   // (32,4096,1) bool->int32
    const float* tw_uniq  = (const float*)d_in[2];   // (32,512,1) f32
    const float* bn_gamma = (const float*)d_in[3];
    const float* bn_beta  = (const float*)d_in[4];
    const float* bn_mean  = (const float*)d_in[5];
    const float* bn_var   = (const float*)d_in[6];
    const float* conv_w   = (const float*)d_in[7];   // (64,128)
    const float* conv_b   = (const float*)d_in[8];   // (64,)
    const float* fc_w     = (const float*)d_in[9];   // (8,64)
    const float* fc_b     = (const float*)d_in[10];  // (8,)
    float* ws  = (float*)d_ws;
    float* out = (float*)d_out;                      // (32,512,8) f32

    prep_kernel<<<1, 256, 0, stream>>>(bn_gamma, bn_beta, bn_mean, bn_var,
                                       conv_w, conv_b, fc_w, fc_b, ws);
    init_out_kernel<<<(B_ * TU * M_) / 256, 256, 0, stream>>>(ws, out);
    scatter_mm_kernel<<<256, 1024, 0, stream>>>(x, mask, tw_uniq, ws, out);
}

// Round 3
// 156.789 us; speedup vs baseline: 1.2090x; 1.2090x over previous
//
#include <hip/hip_runtime.h>

// Problem constants (from reference setup_inputs)
#define B_   32
#define T_   4096
#define D_   128
#define TU   512
#define M_   8
#define O_   64      // Dout
#define DCH  16      // D-chunk per block
#define NCH  8       // number of D-chunks (D_/DCH)
#define PAD  17      // LDS leading-dim pad: (17u+d)%32 conflict-free both phases
#define BN_EPS 1e-5f
#define UB   8       // t-loop load batch depth (24 loads in flight/thread)

// ---------------------------------------------------------------------------
// K1: fold BN + conv + fc into Weff[8][128] and beff[8], stored in ws.
// ws layout (floats): [0,1024) Weff, [1024,1032) beff
// ---------------------------------------------------------------------------
__global__ void prep_kernel(const float* __restrict__ bn_gamma,
                            const float* __restrict__ bn_beta,
                            const float* __restrict__ bn_mean,
                            const float* __restrict__ bn_var,
                            const float* __restrict__ conv_w,
                            const float* __restrict__ conv_b,
                            const float* __restrict__ fc_w,
                            const float* __restrict__ fc_b,
                            float* __restrict__ ws) {
    __shared__ float wraw[M_ * D_];
    __shared__ float shift_s[D_];
    int tid = threadIdx.x;  // 256 threads
    for (int p = tid; p < M_ * D_; p += 256) {
        int m = p >> 7, d = p & (D_ - 1);
        float s = 0.f;
        for (int o = 0; o < O_; ++o) s += fc_w[m * O_ + o] * conv_w[o * D_ + d];
        wraw[p] = s;
        float sc = bn_gamma[d] * rsqrtf(bn_var[d] + BN_EPS);
        ws[p] = s * sc;
    }
    if (tid < D_) {
        float sc = bn_gamma[tid] * rsqrtf(bn_var[tid] + BN_EPS);
        shift_s[tid] = bn_beta[tid] - bn_mean[tid] * sc;
    }
    __syncthreads();
    if (tid < M_) {
        float s = fc_b[tid];
        for (int o = 0; o < O_; ++o) s += fc_w[tid * O_ + o] * conv_b[o];
        for (int d = 0; d < D_; ++d) s += shift_s[d] * wraw[tid * D_ + d];
        ws[M_ * D_ + tid] = s;
    }
}

// ---------------------------------------------------------------------------
// K2: out[b,u,m] = beff[m]  (full overwrite; scatter kernel atomicAdds on top)
// ---------------------------------------------------------------------------
__global__ void init_out_kernel(const float* __restrict__ ws,
                                float* __restrict__ out) {
    int i = blockIdx.x * 256 + threadIdx.x;  // grid covers B_*TU*M_ exactly
    out[i] = ws[M_ * D_ + (i & (M_ - 1))];
}

// ---------------------------------------------------------------------------
// K3: per-(batch b, d-chunk c) block:
//   phase 1: scatter-max masked positive feats into LDS hidden[512][16] (uint bits)
//            -- loads batched UB-deep in register arrays for MLP (R3 change)
//   phase 2: partial[u][m] = sum_{d in chunk} hidden[u][d]*Weff[m][d], atomicAdd out
//
// XCD swizzle (kept from R2, halved HBM fetch): block i -> xcd = i&7; all 8
// chunk-blocks of a batch share one XCD so each 516 B row is fetched once:
//   b = (i&7) + 8*((i>>3)&3) ; c = i>>5
// ---------------------------------------------------------------------------
__global__ __launch_bounds__(1024) void scatter_mm_kernel(
    const float* __restrict__ x,        // (B,T,129): [...,0]=tw, [...,1:]=feats
    const int*   __restrict__ mask,     // (B,T) as int32
    const float* __restrict__ tw_uniq,  // (B,Tu)
    const float* __restrict__ ws,       // Weff + beff
    float*       __restrict__ out) {    // (B,Tu,M)
    __shared__ unsigned hid[TU * PAD];  // 34,816 B
    __shared__ float wsm[M_ * DCH];
    const int i = blockIdx.x;           // 0..255
    const int b = (i & 7) + 8 * ((i >> 3) & 3);
    const int c = i >> 5;               // 0..7
    const int tid = threadIdx.x;

    for (int p = tid; p < TU * PAD; p += 1024) hid[p] = 0u;
    if (tid < M_ * DCH) {
        int m = tid / DCH, d = tid % DCH;
        wsm[tid] = ws[m * D_ + c * DCH + d];
    }
    __syncthreads();

    const float* xb = x + (size_t)b * T_ * (D_ + 1);
    const int*   mb = mask + b * T_;
    const float  u0 = tw_uniq[b * TU];

    const int dl = tid & (DCH - 1);   // 0..15: d within chunk
    const int g  = tid >> 4;          // 0..63: row group
    // 64 t-iterations = 8 outer x UB inner; all UB*3 loads issued before use.
    for (int it = 0; it < T_ / 64 / UB; ++it) {
        float fv[UB], twf[UB];
        int   mk[UB];
#pragma unroll
        for (int j = 0; j < UB; ++j) {
            const int t = (it * UB + j) * 64 + g;
            const float* row = xb + (size_t)t * (D_ + 1);
            fv[j]  = row[1 + c * DCH + dl];
            twf[j] = row[0];
            mk[j]  = mb[t];
        }
#pragma unroll
        for (int j = 0; j < UB; ++j) {
            if (mk[j] != 0 && fv[j] > 0.0f) {
                int u = (int)(twf[j] - u0);
                u = min(max(u, 0), TU - 1);
                atomicMax(&hid[u * PAD + dl], __float_as_uint(fv[j]));
            }
        }
    }
    __syncthreads();

    // epilogue: thread -> (u = tid&511, mh = tid>>9 selects m in [4*mh, 4*mh+4))
    const int u  = tid & (TU - 1);
    const int mh = tid >> 9;
    float a0 = 0.f, a1 = 0.f, a2 = 0.f, a3 = 0.f;
#pragma unroll
    for (int d = 0; d < DCH; ++d) {
        float h = __uint_as_float(hid[u * PAD + d]);  // (17u+d)%32: conflict-free
        a0 += h * wsm[(mh * 4 + 0) * DCH + d];
        a1 += h * wsm[(mh * 4 + 1) * DCH + d];
        a2 += h * wsm[(mh * 4 + 2) * DCH + d];
        a3 += h * wsm[(mh * 4 + 3) * DCH + d];
    }
    float* op = out + ((size_t)(b * TU + u)) * M_ + mh * 4;
    atomicAdd(op + 0, a0);
    atomicAdd(op + 1, a1);
    atomicAdd(op + 2, a2);
    atomicAdd(op + 3, a3);
}

extern "C" void kernel_launch(void* const* d_in, const int* in_sizes, int n_in,
                              void* d_out, int out_size, void* d_ws, size_t ws_size,
                              hipStream_t stream) {
    const float* x        = (const float*)d_in[0];   // (32,4096,129) f32
    const int*   mask     = (const int*)  d_in[1];   // (32,4096,1) bool->int32
    const float* tw_uniq  = (const float*)d_in[2];   // (32,512,1) f32
    const float* bn_gamma = (const float*)d_in[3];
    const float* bn_beta  = (const float*)d_in[4];
    const float* bn_mean  = (const float*)d_in[5];
    const float* bn_var   = (const float*)d_in[6];
    const float* conv_w   = (const float*)d_in[7];   // (64,128)
    const float* conv_b   = (const float*)d_in[8];   // (64,)
    const float* fc_w     = (const float*)d_in[9];   // (8,64)
    const float* fc_b     = (const float*)d_in[10];  // (8,)
    float* ws  = (float*)d_ws;
    float* out = (float*)d_out;                      // (32,512,8) f32

    prep_kernel<<<1, 256, 0, stream>>>(bn_gamma, bn_beta, bn_mean, bn_var,
                                       conv_w, conv_b, fc_w, fc_b, ws);
    init_out_kernel<<<(B_ * TU * M_) / 256, 256, 0, stream>>>(ws, out);
    scatter_mm_kernel<<<256, 1024, 0, stream>>>(x, mask, tw_uniq, ws, out);
}

// Round 4
// 144.324 us; speedup vs baseline: 1.3134x; 1.0864x over previous
//
#include <hip/hip_runtime.h>

// Problem constants (from reference setup_inputs)
#define B_   32
#define T_   4096
#define D_   128
#define TU   512
#define M_   8
#define O_   64      // Dout
#define DCH  16      // D-chunk per block
#define NCH  8       // number of D-chunks (D_/DCH)
#define PAD  17      // LDS leading-dim pad: (17u+d)%32 conflict-free both phases
#define BN_EPS 1e-5f
#define UB   8       // t-loop load batch depth

// ---------------------------------------------------------------------------
// Single fused kernel. Per-(batch b, d-chunk c) block:
//   phase 0: zero LDS hid; threads<128 fold BN+conv+fc for this chunk:
//            Wraw[m][d] = sum_o fc_w[m][o]*conv_w[o][d]
//            wsm[m][dl] = Wraw*scale[d];  tmp = Wraw*shift[d]
//            biasc[m]   = sum_{d in chunk} Wraw*shift  (+ fc_b + fc_w*conv_b
//                         added only by c==0 blocks)
//   phase 1: scatter-max masked positive feats into LDS hid (uint bits;
//            hidden init=0 => only fv>0 matter; uint atomicMax == float max
//            for non-negative floats)
//   phase 2: out[b,u,m] += biasc[m] + sum_{d in chunk} hid[u][d]*wsm[m][d]
//            via global atomicAdd onto memset-zeroed out.
//
// XCD swizzle (R2, halved HBM fetch): block i -> xcd = i&7; all 8 chunk-
// blocks of a batch share one XCD so each 516 B x-row is fetched once:
//   b = (i&7) + 8*((i>>3)&3) ; c = i>>5
// ---------------------------------------------------------------------------
__global__ __launch_bounds__(1024) void fused_scatter_mm_kernel(
    const float* __restrict__ x,        // (B,T,129): [...,0]=tw, [...,1:]=feats
    const int*   __restrict__ mask,     // (B,T) as int32
    const float* __restrict__ tw_uniq,  // (B,Tu)
    const float* __restrict__ bn_gamma,
    const float* __restrict__ bn_beta,
    const float* __restrict__ bn_mean,
    const float* __restrict__ bn_var,
    const float* __restrict__ conv_w,   // (64,128)
    const float* __restrict__ conv_b,   // (64,)
    const float* __restrict__ fc_w,     // (8,64)
    const float* __restrict__ fc_b,     // (8,)
    float*       __restrict__ out) {    // (B,Tu,M), pre-zeroed
    __shared__ unsigned hid[TU * PAD];  // 34,816 B
    __shared__ float wsm[M_ * DCH];
    __shared__ float tmp[M_ * DCH];
    __shared__ float biasc[M_];
    const int i = blockIdx.x;           // 0..255
    const int b = (i & 7) + 8 * ((i >> 3) & 3);
    const int c = i >> 5;               // 0..7
    const int tid = threadIdx.x;

    // ---- phase 0: zero hid + fold weights for this chunk ----
    for (int p = tid; p < TU * PAD; p += 1024) hid[p] = 0u;
    if (tid < M_ * DCH) {
        const int m = tid >> 4, dl = tid & (DCH - 1), d = c * DCH + dl;
        float wraw = 0.f;
#pragma unroll
        for (int o = 0; o < O_; ++o) wraw += fc_w[m * O_ + o] * conv_w[o * D_ + d];
        const float sc = bn_gamma[d] * rsqrtf(bn_var[d] + BN_EPS);
        const float sh = bn_beta[d] - bn_mean[d] * sc;
        wsm[tid] = wraw * sc;
        tmp[tid] = wraw * sh;
    }
    __syncthreads();
    if (tid < M_) {
        float s = 0.f;
#pragma unroll
        for (int d = 0; d < DCH; ++d) s += tmp[tid * DCH + d];
        if (c == 0) {
            s += fc_b[tid];
            for (int o = 0; o < O_; ++o) s += fc_w[tid * O_ + o] * conv_b[o];
        }
        biasc[tid] = s;   // written before phase-1 end barrier; read after it
    }

    // ---- phase 1: scatter-max into LDS ----
    const float* xb = x + (size_t)b * T_ * (D_ + 1);
    const int*   mb = mask + b * T_;
    const float  u0 = tw_uniq[b * TU];

    const int dl = tid & (DCH - 1);   // 0..15: d within chunk
    const int g  = tid >> 4;          // 0..63: row group
    for (int it = 0; it < T_ / 64 / UB; ++it) {
        float fv[UB], twf[UB];
        int   mk[UB];
#pragma unroll
        for (int j = 0; j < UB; ++j) {
            const int t = (it * UB + j) * 64 + g;
            const float* row = xb + (size_t)t * (D_ + 1);
            fv[j]  = row[1 + c * DCH + dl];
            twf[j] = row[0];
            mk[j]  = mb[t];
        }
#pragma unroll
        for (int j = 0; j < UB; ++j) {
            if (mk[j] != 0 && fv[j] > 0.0f) {
                int u = (int)(twf[j] - u0);
                u = min(max(u, 0), TU - 1);
                atomicMax(&hid[u * PAD + dl], __float_as_uint(fv[j]));
            }
        }
    }
    __syncthreads();

    // ---- phase 2: partial matmul + bias, atomicAdd to out ----
    const int u  = tid & (TU - 1);
    const int mh = tid >> 9;          // 0/1 -> m in [4*mh, 4*mh+4)
    float a0 = biasc[mh * 4 + 0];
    float a1 = biasc[mh * 4 + 1];
    float a2 = biasc[mh * 4 + 2];
    float a3 = biasc[mh * 4 + 3];
#pragma unroll
    for (int d = 0; d < DCH; ++d) {
        float h = __uint_as_float(hid[u * PAD + d]);  // (17u+d)%32: conflict-free
        a0 += h * wsm[(mh * 4 + 0) * DCH + d];
        a1 += h * wsm[(mh * 4 + 1) * DCH + d];
        a2 += h * wsm[(mh * 4 + 2) * DCH + d];
        a3 += h * wsm[(mh * 4 + 3) * DCH + d];
    }
    float* op = out + ((size_t)(b * TU + u)) * M_ + mh * 4;
    atomicAdd(op + 0, a0);
    atomicAdd(op + 1, a1);
    atomicAdd(op + 2, a2);
    atomicAdd(op + 3, a3);
}

extern "C" void kernel_launch(void* const* d_in, const int* in_sizes, int n_in,
                              void* d_out, int out_size, void* d_ws, size_t ws_size,
                              hipStream_t stream) {
    const float* x        = (const float*)d_in[0];   // (32,4096,129) f32
    const int*   mask     = (const int*)  d_in[1];   // (32,4096,1) bool->int32
    const float* tw_uniq  = (const float*)d_in[2];   // (32,512,1) f32
    const float* bn_gamma = (const float*)d_in[3];
    const float* bn_beta  = (const float*)d_in[4];
    const float* bn_mean  = (const float*)d_in[5];
    const float* bn_var   = (const float*)d_in[6];
    const float* conv_w   = (const float*)d_in[7];   // (64,128)
    const float* conv_b   = (const float*)d_in[8];   // (64,)
    const float* fc_w     = (const float*)d_in[9];   // (8,64)
    const float* fc_b     = (const float*)d_in[10];  // (8,)
    float* out = (float*)d_out;                      // (32,512,8) f32

    hipMemsetAsync(out, 0, (size_t)out_size * sizeof(float), stream);
    fused_scatter_mm_kernel<<<256, 1024, 0, stream>>>(
        x, mask, tw_uniq, bn_gamma, bn_beta, bn_mean, bn_var,
        conv_w, conv_b, fc_w, fc_b, out);
}

// Round 5
// 128.754 us; speedup vs baseline: 1.4722x; 1.1209x over previous
//
#include <hip/hip_runtime.h>

// Problem constants (from reference setup_inputs)
#define B_   32
#define T_   4096
#define D_   128
#define TU   512
#define M_   8
#define O_   64      // Dout
#define DCH  16      // D-chunk per block
#define NCH  8       // number of D-chunks (D_/DCH)
#define PAD  17      // LDS leading-dim pad: (17u+d)%32 conflict-free both phases
#define BN_EPS 1e-5f
#define UB   4       // t-loop load batch depth (4 x {float4,tw,mask} in flight)

// 16 B vector with 4 B alignment: x rows are 516 B so the 16 B feat windows
// are only element-aligned; this type lets the compiler emit dwordx4 legally
// (gfx950 unaligned-access-mode handles the line straddle in HW).
typedef float f4u __attribute__((ext_vector_type(4), aligned(4)));

// ws layout: partials[c][b][u][m], NCH*B_*TU*M_ floats = 4 MB
#define WS_STRIDE (B_ * TU * M_)

// ---------------------------------------------------------------------------
// K1: per-(batch b, d-chunk c) block:
//   phase 0: zero LDS hid; fold BN+conv+fc for this chunk (Weff, per-chunk bias)
//   phase 1: scatter-max masked positive feats into LDS hid (uint bits;
//            hidden init=0 => only fv>0 matter; uint atomicMax == float max
//            for non-negative floats). float4 loads, UB-deep batching.
//   phase 2: partial[u][m] = biasc[m] + sum_{d in chunk} hid[u][d]*Weff[m][d]
//            stored (non-atomic, 16 B) to ws[c][b][u][m].
//
// XCD swizzle (R2, halved HBM fetch): block i -> xcd = i&7; all 8 chunk-
// blocks of a batch share one XCD so each 516 B x-row is fetched once:
//   b = (i&7) + 8*((i>>3)&3) ; c = i>>5
// ---------------------------------------------------------------------------
__global__ __launch_bounds__(1024) void fused_scatter_mm_kernel(
    const float* __restrict__ x,        // (B,T,129): [...,0]=tw, [...,1:]=feats
    const int*   __restrict__ mask,     // (B,T) as int32
    const float* __restrict__ tw_uniq,  // (B,Tu)
    const float* __restrict__ bn_gamma,
    const float* __restrict__ bn_beta,
    const float* __restrict__ bn_mean,
    const float* __restrict__ bn_var,
    const float* __restrict__ conv_w,   // (64,128)
    const float* __restrict__ conv_b,   // (64,)
    const float* __restrict__ fc_w,     // (8,64)
    const float* __restrict__ fc_b,     // (8,)
    float*       __restrict__ ws) {     // partials[c][b][u][m]
    __shared__ unsigned hid[TU * PAD];  // 34,816 B
    __shared__ float wsm[M_ * DCH];
    __shared__ float tmp[M_ * DCH];
    __shared__ float biasc[M_];
    const int i = blockIdx.x;           // 0..255
    const int b = (i & 7) + 8 * ((i >> 3) & 3);
    const int c = i >> 5;               // 0..7
    const int tid = threadIdx.x;

    // ---- phase 0: zero hid + fold weights for this chunk ----
    for (int p = tid; p < TU * PAD; p += 1024) hid[p] = 0u;
    if (tid < M_ * DCH) {
        const int m = tid >> 4, dl = tid & (DCH - 1), d = c * DCH + dl;
        float wraw = 0.f;
#pragma unroll
        for (int o = 0; o < O_; ++o) wraw += fc_w[m * O_ + o] * conv_w[o * D_ + d];
        const float sc = bn_gamma[d] * rsqrtf(bn_var[d] + BN_EPS);
        const float sh = bn_beta[d] - bn_mean[d] * sc;
        wsm[tid] = wraw * sc;
        tmp[tid] = wraw * sh;
    }
    __syncthreads();
    if (tid < M_) {
        float s = 0.f;
#pragma unroll
        for (int d = 0; d < DCH; ++d) s += tmp[tid * DCH + d];
        if (c == 0) {
            s += fc_b[tid];
            for (int o = 0; o < O_; ++o) s += fc_w[tid * O_ + o] * conv_b[o];
        }
        biasc[tid] = s;   // read after the phase-1 end barrier
    }

    // ---- phase 1: scatter-max into LDS, float4 loads ----
    const float* xb = x + (size_t)b * T_ * (D_ + 1);
    const int*   mb = mask + b * T_;
    const float  u0 = tw_uniq[b * TU];

    const int q = tid & 3;            // quad lane: d = c*16 + q*4 .. +3
    const int r = tid >> 2;           // 0..255: row group
    // 4096 rows = 16 passes of 256 rows = 4 outer x UB inner
    for (int it = 0; it < T_ / 256 / UB; ++it) {
        f4u   fv[UB];
        float twf[UB];
        int   mk[UB];
#pragma unroll
        for (int j = 0; j < UB; ++j) {
            const int t = (it * UB + j) * 256 + r;
            const float* row = xb + (size_t)t * (D_ + 1);
            fv[j]  = *(const f4u*)(row + 1 + c * DCH + q * 4);
            twf[j] = row[0];
            mk[j]  = mb[t];
        }
#pragma unroll
        for (int j = 0; j < UB; ++j) {
            if (mk[j] != 0) {
                int u = min(max((int)(twf[j] - u0), 0), TU - 1);
                unsigned* hp = &hid[u * PAD + q * 4];
                if (fv[j].x > 0.0f) atomicMax(hp + 0, __float_as_uint(fv[j].x));
                if (fv[j].y > 0.0f) atomicMax(hp + 1, __float_as_uint(fv[j].y));
                if (fv[j].z > 0.0f) atomicMax(hp + 2, __float_as_uint(fv[j].z));
                if (fv[j].w > 0.0f) atomicMax(hp + 3, __float_as_uint(fv[j].w));
            }
        }
    }
    __syncthreads();

    // ---- phase 2: partial matmul + bias, plain 16 B store to ws ----
    const int u  = tid & (TU - 1);
    const int mh = tid >> 9;          // 0/1 -> m in [4*mh, 4*mh+4)
    float a0 = biasc[mh * 4 + 0];
    float a1 = biasc[mh * 4 + 1];
    float a2 = biasc[mh * 4 + 2];
    float a3 = biasc[mh * 4 + 3];
#pragma unroll
    for (int d = 0; d < DCH; ++d) {
        float h = __uint_as_float(hid[u * PAD + d]);  // (17u+d)%32: conflict-free
        a0 += h * wsm[(mh * 4 + 0) * DCH + d];
        a1 += h * wsm[(mh * 4 + 1) * DCH + d];
        a2 += h * wsm[(mh * 4 + 2) * DCH + d];
        a3 += h * wsm[(mh * 4 + 3) * DCH + d];
    }
    float4 av = make_float4(a0, a1, a2, a3);
    float* wp = ws + (size_t)c * WS_STRIDE + ((size_t)(b * TU + u)) * M_ + mh * 4;
    *(float4*)wp = av;                // 16 B aligned: index is a multiple of 4
}

// ---------------------------------------------------------------------------
// K2: out[b,u,m] = sum_c partials[c][b][u][m]. 512 blocks x 256 threads,
// 1 element/thread. XCD swizzle matches K1 so batch b's partials are L2-hits:
//   block j: x=j&7, s=j>>3 (0..63); b = x + 8*(s&3); u-chunk = s>>2 (32 u each)
// ---------------------------------------------------------------------------
__global__ __launch_bounds__(256) void reduce_kernel(
    const float* __restrict__ ws, float* __restrict__ out) {
    const int j = blockIdx.x;
    const int s = j >> 3;
    const int b = (j & 7) + 8 * (s & 3);
    const int uc = s >> 2;                       // 0..15
    const int idx = (b * TU + uc * 32) * M_ + threadIdx.x;  // 32 u x 8 m = 256
    float acc = 0.f;
#pragma unroll
    for (int c = 0; c < NCH; ++c) acc += ws[(size_t)c * WS_STRIDE + idx];
    out[idx] = acc;
}

extern "C" void kernel_launch(void* const* d_in, const int* in_sizes, int n_in,
                              void* d_out, int out_size, void* d_ws, size_t ws_size,
                              hipStream_t stream) {
    const float* x        = (const float*)d_in[0];   // (32,4096,129) f32
    const int*   mask     = (const int*)  d_in[1];   // (32,4096,1) bool->int32
    const float* tw_uniq  = (const float*)d_in[2];   // (32,512,1) f32
    const float* bn_gamma = (const float*)d_in[3];
    const float* bn_beta  = (const float*)d_in[4];
    const float* bn_mean  = (const float*)d_in[5];
    const float* bn_var   = (const float*)d_in[6];
    const float* conv_w   = (const float*)d_in[7];   // (64,128)
    const float* conv_b   = (const float*)d_in[8];   // (64,)
    const float* fc_w     = (const float*)d_in[9];   // (8,64)
    const float* fc_b     = (const float*)d_in[10];  // (8,)
    float* ws  = (float*)d_ws;                       // needs 4 MB
    float* out = (float*)d_out;                      // (32,512,8) f32

    fused_scatter_mm_kernel<<<256, 1024, 0, stream>>>(
        x, mask, tw_uniq, bn_gamma, bn_beta, bn_mean, bn_var,
        conv_w, conv_b, fc_w, fc_b, ws);
    reduce_kernel<<<512, 256, 0, stream>>>(ws, out);
}